// Round 3
// baseline (239.062 us; speedup 1.0000x reference)
//
#include <hip/hip_runtime.h>

#define IC 128
#define OC 256
#define RR 64
#define CCOLS 64
#define HO 62
#define WO 62
#define NB 16

// dense bf16 weights: W9T[kpos][oc][c], kpos = ky*3+kx
#define W9T_ELEMS (9 * OC * IC)
#define W9T_BYTES (W9T_ELEMS * 2)
#define LDSROW 16384   // one image row in LDS: 64 x * 256 B (128 c * bf16)

typedef __bf16 bf16x8 __attribute__((ext_vector_type(8)));
typedef float f32x4 __attribute__((ext_vector_type(4)));

__device__ __forceinline__ unsigned short f2bf(float f) {
    unsigned u = __builtin_bit_cast(unsigned, f);
    u += 0x7FFFu + ((u >> 16) & 1u);   // round-to-nearest-even
    return (unsigned short)(u >> 16);
}

__global__ void prep_weights(const float* __restrict__ wv,
                             const int* __restrict__ iwi,
                             const int* __restrict__ flen,
                             const int* __restrict__ sp,
                             unsigned short* __restrict__ W9T) {
    const int oc = blockIdx.x;
    const int s = sp[oc];
    const int n = flen[oc];
    for (int t = threadIdx.x; t < n; t += blockDim.x) {
        const int ix = iwi[s + t];          // c*4096 + ky*64 + kx
        const int c = ix >> 12;
        const int rem = ix & 4095;
        const int ky = rem >> 6, kx = rem & 63;
        W9T[((ky * 3 + kx) * OC + oc) * IC + c] = f2bf(wv[s + t]);
    }
}

__global__ void bias_kernel(const int* __restrict__ bias_index,
                            const float* __restrict__ bias_value,
                            float* __restrict__ bias_dense, int nbias) {
    int t = threadIdx.x;
    if (t < OC) bias_dense[t] = 0.f;
    __syncthreads();
    if (t < nbias) atomicAdd(&bias_dense[bias_index[t]], bias_value[t]);
}

// Block = (b, y-tile of 2 rows) x all 256 oc. 512 threads = 8 waves.
// Wave w: oc in [32w, 32w+32) (2 m-tiles), n = 2 y-rows x 4 x-tiles.
// LDS: image rows y0..y0+3, x-major bf16 [4][64x][128c], XOR-swizzled.
__global__ __launch_bounds__(512, 4) void conv_mfma(
    const float* __restrict__ images,
    const unsigned short* __restrict__ W9T,
    const float* __restrict__ bias_dense,
    float* __restrict__ out)
{
    const int y0 = blockIdx.x * 2;
    const int b = blockIdx.y;
    const int t = threadIdx.x;
    const int w = t >> 6;
    const int l = t & 63;
    const int lq = l >> 4, lr = l & 15;

    __shared__ unsigned char lds[4 * LDSROW];   // 65536 B

    const float* __restrict__ imgb = images + (size_t)b * (IC * RR * CCOLS);

    // ---- stage 4 image rows, fp32 -> bf16, transposed to [x][c], swizzled ----
    {
        const int xg = (t & 15) << 2;   // 4 consecutive x per thread
        const int cp = t >> 4;          // 0..31 channel-pair index
        #pragma unroll
        for (int p = 0; p < 8; ++p) {
            const int krow = p >> 1;
            const int c = ((p & 1) << 6) + (cp << 1);       // even channel
            const float* p0 = imgb + c * (RR * CCOLS) + (y0 + krow) * CCOLS + xg;
            const float4 r0 = *(const float4*)p0;
            const float4 r1 = *(const float4*)(p0 + RR * CCOLS);
            const float a0[4] = {r0.x, r0.y, r0.z, r0.w};
            const float a1[4] = {r1.x, r1.y, r1.z, r1.w};
            #pragma unroll
            for (int i = 0; i < 4; ++i) {
                const int x = xg + i;
                const unsigned v = (unsigned)f2bf(a0[i]) | ((unsigned)f2bf(a1[i]) << 16);
                *(unsigned*)(lds + krow * LDSROW + x * 256 +
                             ((c * 2) ^ ((x & 7) << 4))) = v;
            }
        }
    }

    const int ocw = 32 * w;
    const int cbase = 8 * lq;           // this lane's k-slice offset

    // issue first A-fragment loads before the barrier (global only, no hazard)
    const unsigned short* __restrict__ A0 = W9T + (ocw + lr) * IC;
    bf16x8 a0c = *(const bf16x8*)(A0 + cbase);
    bf16x8 a1c = *(const bf16x8*)(A0 + 16 * IC + cbase);

    __syncthreads();

    f32x4 acc[2][2][4] = {};

    #pragma unroll
    for (int kp = 0; kp < 9; ++kp) {
        const int ky = kp / 3, kx = kp % 3;              // compile-time
        const unsigned char* __restrict__ r0 = lds + ky * LDSROW;
        #pragma unroll
        for (int ci = 0; ci < 4; ++ci) {
            const int cl = ci * 32 + cbase;
            // ---- prefetch next chunk's A-fragments (double-buffer) ----
            bf16x8 a0n, a1n;
            const bool last = (kp == 8) && (ci == 3);
            if (!last) {
                const int nkp = (ci == 3) ? kp + 1 : kp;
                const int ncl = (ci == 3) ? cbase : cl + 32;
                const unsigned short* __restrict__ An =
                    W9T + (nkp * OC + ocw + lr) * IC + ncl;
                a0n = *(const bf16x8*)An;
                a1n = *(const bf16x8*)(An + 16 * IC);
            }
            const int slot = cl * 2;
            #pragma unroll
            for (int yy = 0; yy < 2; ++yy) {
                const unsigned char* __restrict__ rr = r0 + yy * LDSROW;
                #pragma unroll
                for (int n = 0; n < 4; ++n) {
                    int x = 16 * n + lr + kx;
                    x = x > 63 ? 63 : x;   // pad lanes: dup col 63 (discarded)
                    const bf16x8 bf = *(const bf16x8*)(
                        rr + x * 256 + (slot ^ ((x & 7) << 4)));
                    acc[0][yy][n] = __builtin_amdgcn_mfma_f32_16x16x32_bf16(
                        a0c, bf, acc[0][yy][n], 0, 0, 0);
                    acc[1][yy][n] = __builtin_amdgcn_mfma_f32_16x16x32_bf16(
                        a1c, bf, acc[1][yy][n], 0, 0, 0);
                }
            }
            if (!last) { a0c = a0n; a1c = a1n; }
        }
    }

    // ---- epilogue: bias + store (C/D: col = lane&15, row = 4*lq + r) ----
    #pragma unroll
    for (int m = 0; m < 2; ++m) {
        const int ocb = ocw + 16 * m + 4 * lq;
        float bv[4];
        #pragma unroll
        for (int r = 0; r < 4; ++r) bv[r] = bias_dense[ocb + r];
        #pragma unroll
        for (int yy = 0; yy < 2; ++yy) {
            #pragma unroll
            for (int n = 0; n < 4; ++n) {
                const int x = 16 * n + lr;
                if (x < WO) {
                    #pragma unroll
                    for (int r = 0; r < 4; ++r)
                        out[(((size_t)b * OC + ocb + r) * HO + (y0 + yy)) * WO + x] =
                            acc[m][yy][n][r] + bv[r];
                }
            }
        }
    }
}

extern "C" void kernel_launch(void* const* d_in, const int* in_sizes, int n_in,
                              void* d_out, int out_size, void* d_ws, size_t ws_size,
                              hipStream_t stream) {
    const float* images             = (const float*)d_in[0];
    const float* weight_value       = (const float*)d_in[1];
    const int*   image_weight_index = (const int*)d_in[2];
    const int*   filter_lengths     = (const int*)d_in[3];
    const int*   start_points       = (const int*)d_in[4];
    const int*   bias_index         = (const int*)d_in[5];
    const float* bias_value         = (const float*)d_in[6];
    float* out = (float*)d_out;

    unsigned short* W9T = (unsigned short*)d_ws;
    float* bias_dense = (float*)((char*)d_ws + W9T_BYTES);

    hipMemsetAsync(d_ws, 0, W9T_BYTES, stream);
    prep_weights<<<OC, 256, 0, stream>>>(weight_value, image_weight_index,
                                         filter_lengths, start_points, W9T);
    bias_kernel<<<1, 256, 0, stream>>>(bias_index, bias_value, bias_dense,
                                       in_sizes[5]);

    dim3 grid(HO / 2, NB);
    conv_mfma<<<grid, 512, 0, stream>>>(images, W9T, bias_dense, out);
}

// Round 4
// 118.767 us; speedup vs baseline: 2.0129x; 2.0129x over previous
//
#include <hip/hip_runtime.h>

#define IC 128
#define OC 256
#define RR 64
#define CCOLS 64
#define HO 62
#define WO 62
#define NB 16

// dense bf16 weights: W9T[kpos][oc][c], kpos = ky*3+kx
#define W9T_ELEMS (9 * OC * IC)
#define W9T_BYTES (W9T_ELEMS * 2)
#define LDSROW 16384   // one image row in LDS: 64 x * 256 B (128 c * bf16)

typedef __bf16 bf16x8 __attribute__((ext_vector_type(8)));
typedef float f32x4 __attribute__((ext_vector_type(4)));

__device__ __forceinline__ unsigned short f2bf(float f) {
    unsigned u = __builtin_bit_cast(unsigned, f);
    u += 0x7FFFu + ((u >> 16) & 1u);   // round-to-nearest-even
    return (unsigned short)(u >> 16);
}

__global__ void prep_weights(const float* __restrict__ wv,
                             const int* __restrict__ iwi,
                             const int* __restrict__ flen,
                             const int* __restrict__ sp,
                             unsigned short* __restrict__ W9T) {
    const int oc = blockIdx.x;
    const int s = sp[oc];
    const int n = flen[oc];
    for (int t = threadIdx.x; t < n; t += blockDim.x) {
        const int ix = iwi[s + t];          // c*4096 + ky*64 + kx
        const int c = ix >> 12;
        const int rem = ix & 4095;
        const int ky = rem >> 6, kx = rem & 63;
        W9T[((ky * 3 + kx) * OC + oc) * IC + c] = f2bf(wv[s + t]);
    }
}

__global__ void bias_kernel(const int* __restrict__ bias_index,
                            const float* __restrict__ bias_value,
                            float* __restrict__ bias_dense, int nbias) {
    int t = threadIdx.x;
    if (t < OC) bias_dense[t] = 0.f;
    __syncthreads();
    if (t < nbias) atomicAdd(&bias_dense[bias_index[t]], bias_value[t]);
}

// Block = (b, y-tile of 2 rows) x all 256 oc. 512 threads = 8 waves.
// Wave w: oc in [32w, 32w+32) (2 m-tiles), n = 2 y-rows x 4 x-tiles.
// LDS: image rows y0..y0+3, x-major bf16 [4][64x][128c], XOR-swizzled.
// launch_bounds(512, 2): 2 waves/EU min -> VGPR cap 256 (4 waves/EU cap of 64
// in R3 spilled the 64-VGPR accumulator to scratch: WRITE_SIZE 458 MB).
__global__ __launch_bounds__(512, 2) void conv_mfma(
    const float* __restrict__ images,
    const unsigned short* __restrict__ W9T,
    const float* __restrict__ bias_dense,
    float* __restrict__ out)
{
    const int y0 = blockIdx.x * 2;
    const int b = blockIdx.y;
    const int t = threadIdx.x;
    const int w = t >> 6;
    const int l = t & 63;
    const int lq = l >> 4, lr = l & 15;

    __shared__ unsigned char lds[4 * LDSROW];   // 65536 B

    const float* __restrict__ imgb = images + (size_t)b * (IC * RR * CCOLS);

    // ---- stage 4 image rows, fp32 -> bf16, transposed to [x][c], swizzled ----
    {
        const int xg = (t & 15) << 2;   // 4 consecutive x per thread
        const int cp = t >> 4;          // 0..31 channel-pair index
        #pragma unroll
        for (int p = 0; p < 8; ++p) {
            const int krow = p >> 1;
            const int c = ((p & 1) << 6) + (cp << 1);       // even channel
            const float* p0 = imgb + c * (RR * CCOLS) + (y0 + krow) * CCOLS + xg;
            const float4 r0 = *(const float4*)p0;
            const float4 r1 = *(const float4*)(p0 + RR * CCOLS);
            const float a0[4] = {r0.x, r0.y, r0.z, r0.w};
            const float a1[4] = {r1.x, r1.y, r1.z, r1.w};
            #pragma unroll
            for (int i = 0; i < 4; ++i) {
                const int x = xg + i;
                const unsigned v = (unsigned)f2bf(a0[i]) | ((unsigned)f2bf(a1[i]) << 16);
                *(unsigned*)(lds + krow * LDSROW + x * 256 +
                             ((c * 2) ^ ((x & 7) << 4))) = v;
            }
        }
    }

    const int ocw = 32 * w;
    const int cbase = 8 * lq;           // this lane's k-slice offset

    // issue first A-fragment loads before the barrier (global only, no hazard)
    const unsigned short* __restrict__ A0 = W9T + (ocw + lr) * IC;
    bf16x8 a0c = *(const bf16x8*)(A0 + cbase);
    bf16x8 a1c = *(const bf16x8*)(A0 + 16 * IC + cbase);

    __syncthreads();

    f32x4 acc[2][2][4] = {};

    #pragma unroll
    for (int kp = 0; kp < 9; ++kp) {
        const int ky = kp / 3, kx = kp % 3;              // compile-time
        const unsigned char* __restrict__ r0 = lds + ky * LDSROW;
        #pragma unroll
        for (int ci = 0; ci < 4; ++ci) {
            const int cl = ci * 32 + cbase;
            // ---- prefetch next chunk's A-fragments (double-buffer) ----
            bf16x8 a0n, a1n;
            const bool last = (kp == 8) && (ci == 3);
            if (!last) {
                const int nkp = (ci == 3) ? kp + 1 : kp;
                const int ncl = (ci == 3) ? cbase : cl + 32;
                const unsigned short* __restrict__ An =
                    W9T + (nkp * OC + ocw + lr) * IC + ncl;
                a0n = *(const bf16x8*)An;
                a1n = *(const bf16x8*)(An + 16 * IC);
            }
            const int slot = cl * 2;
            #pragma unroll
            for (int yy = 0; yy < 2; ++yy) {
                const unsigned char* __restrict__ rr = r0 + yy * LDSROW;
                #pragma unroll
                for (int n = 0; n < 4; ++n) {
                    int x = 16 * n + lr + kx;
                    x = x > 63 ? 63 : x;   // pad lanes: dup col 63 (discarded)
                    const bf16x8 bf = *(const bf16x8*)(
                        rr + x * 256 + (slot ^ ((x & 7) << 4)));
                    acc[0][yy][n] = __builtin_amdgcn_mfma_f32_16x16x32_bf16(
                        a0c, bf, acc[0][yy][n], 0, 0, 0);
                    acc[1][yy][n] = __builtin_amdgcn_mfma_f32_16x16x32_bf16(
                        a1c, bf, acc[1][yy][n], 0, 0, 0);
                }
            }
            if (!last) { a0c = a0n; a1c = a1n; }
        }
    }

    // ---- epilogue: bias + store (C/D: col = lane&15, row = 4*lq + r) ----
    #pragma unroll
    for (int m = 0; m < 2; ++m) {
        const int ocb = ocw + 16 * m + 4 * lq;
        float bv[4];
        #pragma unroll
        for (int r = 0; r < 4; ++r) bv[r] = bias_dense[ocb + r];
        #pragma unroll
        for (int yy = 0; yy < 2; ++yy) {
            #pragma unroll
            for (int n = 0; n < 4; ++n) {
                const int x = 16 * n + lr;
                if (x < WO) {
                    #pragma unroll
                    for (int r = 0; r < 4; ++r)
                        out[(((size_t)b * OC + ocb + r) * HO + (y0 + yy)) * WO + x] =
                            acc[m][yy][n][r] + bv[r];
                }
            }
        }
    }
}

extern "C" void kernel_launch(void* const* d_in, const int* in_sizes, int n_in,
                              void* d_out, int out_size, void* d_ws, size_t ws_size,
                              hipStream_t stream) {
    const float* images             = (const float*)d_in[0];
    const float* weight_value       = (const float*)d_in[1];
    const int*   image_weight_index = (const int*)d_in[2];
    const int*   filter_lengths     = (const int*)d_in[3];
    const int*   start_points       = (const int*)d_in[4];
    const int*   bias_index         = (const int*)d_in[5];
    const float* bias_value         = (const float*)d_in[6];
    float* out = (float*)d_out;

    unsigned short* W9T = (unsigned short*)d_ws;
    float* bias_dense = (float*)((char*)d_ws + W9T_BYTES);

    hipMemsetAsync(d_ws, 0, W9T_BYTES, stream);
    prep_weights<<<OC, 256, 0, stream>>>(weight_value, image_weight_index,
                                         filter_lengths, start_points, W9T);
    bias_kernel<<<1, 256, 0, stream>>>(bias_index, bias_value, bias_dense,
                                       in_sizes[5]);

    dim3 grid(HO / 2, NB);
    conv_mfma<<<grid, 512, 0, stream>>>(images, W9T, bias_dense, out);
}

// Round 5
// 95.937 us; speedup vs baseline: 2.4919x; 1.2380x over previous
//
#include <hip/hip_runtime.h>

#define IC 128
#define OC 256
#define RR 64
#define CCOLS 64
#define HO 62
#define WO 62
#define NB 16

// dense bf16 weights: W9T[kpos][oc][c], kpos = ky*3+kx
#define W9T_ELEMS (9 * OC * IC)
#define W9T_BYTES (W9T_ELEMS * 2)
#define LDSROW 16384   // one image row in LDS: 64 x * 256 B (128 c * bf16)

typedef __bf16 bf16x8 __attribute__((ext_vector_type(8)));
typedef float f32x4 __attribute__((ext_vector_type(4)));

__device__ __forceinline__ unsigned short f2bf(float f) {
    unsigned u = __builtin_bit_cast(unsigned, f);
    u += 0x7FFFu + ((u >> 16) & 1u);   // round-to-nearest-even
    return (unsigned short)(u >> 16);
}

__global__ void prep_weights(const float* __restrict__ wv,
                             const int* __restrict__ iwi,
                             const int* __restrict__ flen,
                             const int* __restrict__ sp,
                             unsigned short* __restrict__ W9T) {
    const int oc = blockIdx.x;
    const int s = sp[oc];
    const int n = flen[oc];
    for (int t = threadIdx.x; t < n; t += blockDim.x) {
        const int ix = iwi[s + t];          // c*4096 + ky*64 + kx
        const int c = ix >> 12;
        const int rem = ix & 4095;
        const int ky = rem >> 6, kx = rem & 63;
        W9T[((ky * 3 + kx) * OC + oc) * IC + c] = f2bf(wv[s + t]);
    }
}

__global__ void bias_kernel(const int* __restrict__ bias_index,
                            const float* __restrict__ bias_value,
                            float* __restrict__ bias_dense, int nbias) {
    int t = threadIdx.x;
    if (t < OC) bias_dense[t] = 0.f;
    __syncthreads();
    if (t < nbias) atomicAdd(&bias_dense[bias_index[t]], bias_value[t]);
}

// Block = one output row (b, y) x all 256 oc. 512 threads = 8 waves.
// Wave w: oc in [32w, 32w+32) (2 m-tiles), x in [0,64) (4 n-tiles).
// LDS: image rows y..y+2, x-major bf16 [3][64x][128c], XOR-swizzled.
// Registers: acc 32 + A-dbuf 16 + temps ~50 -> fits the 128 cap of (512,2)
// (R3/R4 lesson: cap = 256/min_waves_per_EU; acc[2][2][4] spilled).
__global__ __launch_bounds__(512, 2) void conv_mfma(
    const float* __restrict__ images,
    const unsigned short* __restrict__ W9T,
    const float* __restrict__ bias_dense,
    float* __restrict__ out)
{
    const int y = blockIdx.x;
    const int b = blockIdx.y;
    const int t = threadIdx.x;
    const int w = t >> 6;
    const int l = t & 63;
    const int lq = l >> 4, lr = l & 15;

    __shared__ unsigned char lds[3 * LDSROW];   // 49152 B

    const float* __restrict__ imgb = images + (size_t)b * (IC * RR * CCOLS);

    // ---- stage 3 image rows, fp32 -> bf16, [x][c] with XOR swizzle ----
    // Thread t: one x = t&63, channel-octet oct = t>>6 (uniform per wave).
    // ds_write_b128: 8 lanes per 16B slot x 4 banks = 8 words/bank = wave64
    // minimum -> conflict-free (R2's u32 staging was 8-way conflicted).
    {
        const int xs = t & 63;
        const int oct = t >> 6;             // 0..7
        const int swz = (xs & 7) << 4;
        #pragma unroll
        for (int krow = 0; krow < 3; ++krow) {
            #pragma unroll
            for (int h = 0; h < 2; ++h) {
                const int c0 = (oct + 8 * h) * 8;   // octet base channel
                const float* __restrict__ p =
                    imgb + (size_t)c0 * (RR * CCOLS) + (y + krow) * CCOLS + xs;
                unsigned v0, v1, v2, v3;
                v0 = (unsigned)f2bf(p[0])              | ((unsigned)f2bf(p[RR * CCOLS])     << 16);
                v1 = (unsigned)f2bf(p[2 * RR * CCOLS]) | ((unsigned)f2bf(p[3 * RR * CCOLS]) << 16);
                v2 = (unsigned)f2bf(p[4 * RR * CCOLS]) | ((unsigned)f2bf(p[5 * RR * CCOLS]) << 16);
                v3 = (unsigned)f2bf(p[6 * RR * CCOLS]) | ((unsigned)f2bf(p[7 * RR * CCOLS]) << 16);
                *(uint4*)(lds + krow * LDSROW + xs * 256 + ((c0 * 2) ^ swz)) =
                    make_uint4(v0, v1, v2, v3);
            }
        }
    }

    const int ocw = 32 * w;
    const int cbase = 8 * lq;           // this lane's k-slice offset

    // issue first A-fragment loads before the barrier (global only, no hazard)
    const unsigned short* __restrict__ A0 = W9T + (ocw + lr) * IC;
    bf16x8 a0c = *(const bf16x8*)(A0 + cbase);
    bf16x8 a1c = *(const bf16x8*)(A0 + 16 * IC + cbase);

    __syncthreads();

    f32x4 acc[2][4] = {};

    #pragma unroll
    for (int kp = 0; kp < 9; ++kp) {
        const int ky = kp / 3, kx = kp % 3;              // compile-time
        const unsigned char* __restrict__ row = lds + ky * LDSROW;
        #pragma unroll
        for (int ci = 0; ci < 4; ++ci) {
            const int cl = ci * 32 + cbase;
            // ---- prefetch next chunk's A-fragments (double-buffer) ----
            bf16x8 a0n, a1n;
            const bool last = (kp == 8) && (ci == 3);
            if (!last) {
                const int nkp = (ci == 3) ? kp + 1 : kp;
                const int ncl = (ci == 3) ? cbase : cl + 32;
                const unsigned short* __restrict__ An =
                    W9T + (nkp * OC + ocw + lr) * IC + ncl;
                a0n = *(const bf16x8*)An;
                a1n = *(const bf16x8*)(An + 16 * IC);
            }
            const int slot = cl * 2;
            #pragma unroll
            for (int n = 0; n < 4; ++n) {
                int x = 16 * n + lr + kx;
                x = x > 63 ? 63 : x;   // pad lanes: dup col 63 (discarded)
                const bf16x8 bf = *(const bf16x8*)(
                    row + x * 256 + (slot ^ ((x & 7) << 4)));
                acc[0][n] = __builtin_amdgcn_mfma_f32_16x16x32_bf16(
                    a0c, bf, acc[0][n], 0, 0, 0);
                acc[1][n] = __builtin_amdgcn_mfma_f32_16x16x32_bf16(
                    a1c, bf, acc[1][n], 0, 0, 0);
            }
            if (!last) { a0c = a0n; a1c = a1n; }
        }
    }

    // ---- epilogue: bias + store (C/D: col = lane&15, row = 4*lq + r) ----
    #pragma unroll
    for (int m = 0; m < 2; ++m) {
        const int ocb = ocw + 16 * m + 4 * lq;
        float bv[4];
        #pragma unroll
        for (int r = 0; r < 4; ++r) bv[r] = bias_dense[ocb + r];
        #pragma unroll
        for (int n = 0; n < 4; ++n) {
            const int x = 16 * n + lr;
            if (x < WO) {
                #pragma unroll
                for (int r = 0; r < 4; ++r)
                    out[(((size_t)b * OC + ocb + r) * HO + y) * WO + x] =
                        acc[m][n][r] + bv[r];
            }
        }
    }
}

extern "C" void kernel_launch(void* const* d_in, const int* in_sizes, int n_in,
                              void* d_out, int out_size, void* d_ws, size_t ws_size,
                              hipStream_t stream) {
    const float* images             = (const float*)d_in[0];
    const float* weight_value       = (const float*)d_in[1];
    const int*   image_weight_index = (const int*)d_in[2];
    const int*   filter_lengths     = (const int*)d_in[3];
    const int*   start_points       = (const int*)d_in[4];
    const int*   bias_index         = (const int*)d_in[5];
    const float* bias_value         = (const float*)d_in[6];
    float* out = (float*)d_out;

    unsigned short* W9T = (unsigned short*)d_ws;
    float* bias_dense = (float*)((char*)d_ws + W9T_BYTES);

    hipMemsetAsync(d_ws, 0, W9T_BYTES, stream);
    prep_weights<<<OC, 256, 0, stream>>>(weight_value, image_weight_index,
                                         filter_lengths, start_points, W9T);
    bias_kernel<<<1, 256, 0, stream>>>(bias_index, bias_value, bias_dense,
                                       in_sizes[5]);

    dim3 grid(HO, NB);
    conv_mfma<<<grid, 512, 0, stream>>>(images, W9T, bias_dense, out);
}